// Round 10
// baseline (348.948 us; speedup 1.0000x reference)
//
#include <hip/hip_runtime.h>

// VQ-VAE vector quantizer forward (fp32).
// inputs: (32,256,32,32) f32 -> flat rows N=32768 x D=256
// embedding: (D=256, K=1024) f32, cluster_size: (1024,) f32
// outputs (flat f32): quantized[N*D], vq_loss, perplexity, code_usage, indices[N] (as float)

constexpr int DIM = 256;   // embedding dim
constexpr int NK  = 1024;  // number of codes
constexpr int RR  = 16;    // input rows per block

// async 16B global->LDS. HW dest = wave-uniform base + lane*16; all call
// sites pass exactly base + 16*lane (k0 = tid*4 floats).
#define GLL16(GSRC, LDST)                                                      \
  __builtin_amdgcn_global_load_lds(                                            \
      (const __attribute__((address_space(1))) void*)(GSRC),                   \
      (__attribute__((address_space(3))) void*)(LDST), 16, 0, 0)

// ---------------------------------------------------------------- enorm (0.5*|e_k|^2)
__global__ __launch_bounds__(256) void enorm_kernel(
    const float* __restrict__ emb, float* __restrict__ enorm) {
  int k = blockIdx.x * 256 + threadIdx.x;
  float s = 0.f;
  for (int d = 0; d < DIM; ++d) {
    float e = emb[(size_t)d * NK + k];
    s = fmaf(e, e, s);
  }
  enorm[k] = 0.5f * s;                   // argmin(|e|^2-2x.e) == argmin(0.5|e|^2-x.e)
}

// ---------------------------------------------------------------- argmin
// 256 threads = 4 waves; 16 rows/block; thread owns codes k0..k0+3 (k0=4*tid).
// x is BLOCK-UNIFORM data: read with uniform-address loads (same address on
// all lanes -> SGPR/scalar path or uniform VMEM; either is correct here).
// No xs LDS tile, no readlane, no per-lane x loads.
// es: R5 self-staged global_load_lds double-buffer (each thread stages &
// reads only its own 4 columns -> no barriers in the loop).
// FIFO invariant (holds whether x-loads are SMEM or VMEM, any order):
//   wait vmcnt(4) at iter g drains S(g) and x(g), leaves S(g+1)x4 in flight.
#define STAGE(G, P)                                                            \
  { const float* _s = emb + ((size_t)(4 * (G)) << 10) + k0;                    \
    GLL16(_s,          &es[(P)][0][k0]);                                       \
    GLL16(_s + NK,     &es[(P)][1][k0]);                                       \
    GLL16(_s + 2 * NK, &es[(P)][2][k0]);                                       \
    GLL16(_s + 3 * NK, &es[(P)][3][k0]); }

// uniform x loads for 4-dim group G into the named register array XA
#define XLOAD(XA, G)                                                           \
  _Pragma("unroll")                                                            \
  for (int r = 0; r < RR; ++r)                                                 \
    XA[r] = *(const float4*)&xg[r * DIM + 4 * (G)];

#define COMPUTE4(PAR, XA)                                                      \
  { const float4 e0 = *(const float4*)&es[(PAR)][0][k0];                       \
    const float4 e1 = *(const float4*)&es[(PAR)][1][k0];                       \
    const float4 e2 = *(const float4*)&es[(PAR)][2][k0];                       \
    const float4 e3 = *(const float4*)&es[(PAR)][3][k0];                       \
    _Pragma("unroll")                                                          \
    for (int r = 0; r < RR; ++r) {                                             \
      const float4 xv = XA[r];                                                 \
      acc[r][0] = fmaf(xv.x, e0.x, fmaf(xv.y, e1.x, fmaf(xv.z, e2.x, fmaf(xv.w, e3.x, acc[r][0])))); \
      acc[r][1] = fmaf(xv.x, e0.y, fmaf(xv.y, e1.y, fmaf(xv.z, e2.y, fmaf(xv.w, e3.y, acc[r][1])))); \
      acc[r][2] = fmaf(xv.x, e0.z, fmaf(xv.y, e1.z, fmaf(xv.z, e2.z, fmaf(xv.w, e3.z, acc[r][2])))); \
      acc[r][3] = fmaf(xv.x, e0.w, fmaf(xv.y, e1.w, fmaf(xv.z, e2.w, fmaf(xv.w, e3.w, acc[r][3])))); \
    } }

#define SB __builtin_amdgcn_sched_barrier(0);

__global__ __launch_bounds__(256, 2) void argmin_kernel(
    const float* __restrict__ x, const float* __restrict__ emb,
    const float* __restrict__ enorm, int* __restrict__ idx_out,
    float* __restrict__ idx_out_f) {
  __shared__ float es[2][4][NK];   // 32 KB double-buffered e-tile
  __shared__ float red_v[4][RR];
  __shared__ int   red_i[4][RR];

  const int tid  = threadIdx.x;
  const int lane = tid & 63;
  const int wv   = tid >> 6;
  const int k0   = tid * 4;
  const float* xg = x + (size_t)blockIdx.x * (RR * DIM);   // block-uniform base

  STAGE(0, 0)
  STAGE(1, 1)
  asm volatile("s_waitcnt vmcnt(4)" ::: "memory");  // S0 landed; S1 in flight
  SB

  float4 xA[RR], xB[RR];
  XLOAD(xA, 0)

  float acc[RR][4];
  #pragma unroll
  for (int r = 0; r < RR; ++r)
    #pragma unroll
    for (int j = 0; j < 4; ++j) acc[r][j] = 0.f;

  #pragma unroll 1
  for (int gg = 0; gg < 32; ++gg) {
    const int g0 = 2 * gg;       // 0..62 (even; parity 0)
    const int g1 = g0 + 1;       // 1..63 (odd;  parity 1)

    // ---- even group g0: use xA, prefetch xB(g1), stage g0+2
    asm volatile("s_waitcnt vmcnt(4)" ::: "memory");  // drains S(g0)+x(g0); S(g0+1) in flight
    SB
    XLOAD(xB, g1)
    COMPUTE4(0, xA)
    SB
    if (gg <= 30) STAGE(g0 + 2, 0)

    // ---- odd group g1: use xB, prefetch xA(g1+1), stage g1+2
    if (gg < 31) {
      asm volatile("s_waitcnt vmcnt(4)" ::: "memory");
    } else {
      asm volatile("s_waitcnt vmcnt(0)" ::: "memory");  // last group: drain all
    }
    SB
    if (gg <= 30) XLOAD(xA, g1 + 1)
    COMPUTE4(1, xB)
    SB
    if (gg <= 30) STAGE(g1 + 2, 1)
  }

  const float4 en = *(const float4*)(enorm + k0);   // 0.5*|e|^2

  for (int r = 0; r < RR; ++r) {
    // score = 0.5|e|^2 - x.e ; strict < keeps lowest index on ties
    float bv = en.x - acc[r][0];
    int   bi = k0;
    { float v = en.y - acc[r][1]; if (v < bv) { bv = v; bi = k0 + 1; } }
    { float v = en.z - acc[r][2]; if (v < bv) { bv = v; bi = k0 + 2; } }
    { float v = en.w - acc[r][3]; if (v < bv) { bv = v; bi = k0 + 3; } }
    for (int off = 32; off > 0; off >>= 1) {
      float ov = __shfl_xor(bv, off);
      int   oi = __shfl_xor(bi, off);
      if (ov < bv || (ov == bv && oi < bi)) { bv = ov; bi = oi; }
    }
    if (lane == 0) { red_v[wv][r] = bv; red_i[wv][r] = bi; }
  }
  __syncthreads();

  if (tid < RR) {
    float bv = red_v[0][tid];
    int   bi = red_i[0][tid];
    #pragma unroll
    for (int w = 1; w < 4; ++w) {
      float v = red_v[w][tid]; int i2 = red_i[w][tid];
      if (v < bv || (v == bv && i2 < bi)) { bv = v; bi = i2; }
    }
    const int n = blockIdx.x * RR + tid;
    idx_out[n]   = bi;
    idx_out_f[n] = (float)bi;
  }
}

// ---------------------------------------------------------------- gather + loss partials
__global__ __launch_bounds__(256) void gather_loss_kernel(
    const float* __restrict__ x, const float* __restrict__ emb,
    const int* __restrict__ idx, float* __restrict__ out_q,
    float* __restrict__ partial) {
  const int tid = threadIdx.x;
  const size_t base = (size_t)blockIdx.x * 2048;
  float local = 0.f;
  #pragma unroll
  for (int h = 0; h < 2; ++h) {
    const size_t g = base + (size_t)h * 1024 + (size_t)tid * 4;
    const int n = (int)(g >> 8);
    const int d = (int)(g & 255);
    const int k = idx[n];
    const float* ep = emb + (size_t)d * NK + k;
    float4 q;
    q.x = ep[0]; q.y = ep[NK]; q.z = ep[2 * NK]; q.w = ep[3 * NK];
    const float4 xv = *(const float4*)(x + g);
    *(float4*)(out_q + g) = q;
    const float dx = q.x - xv.x, dy = q.y - xv.y, dz = q.z - xv.z, dw = q.w - xv.w;
    local = fmaf(dx, dx, local);
    local = fmaf(dy, dy, local);
    local = fmaf(dz, dz, local);
    local = fmaf(dw, dw, local);
  }
  for (int off = 32; off > 0; off >>= 1) local += __shfl_down(local, off);
  __shared__ float wsum[4];
  if ((tid & 63) == 0) wsum[tid >> 6] = local;
  __syncthreads();
  if (tid == 0) partial[blockIdx.x] = (wsum[0] + wsum[1]) + (wsum[2] + wsum[3]);
}

// ---------------------------------------------------------------- finalize scalars
__global__ __launch_bounds__(1024) void finalize_kernel(
    const float* __restrict__ partial, int np,
    const float* __restrict__ cs, float* __restrict__ out_s,
    float inv_count) {
  __shared__ float sd[1024];
  const int tid = threadIdx.x;

  float s = 0.f;
  for (int i = tid; i < np; i += 1024) s += partial[i];
  sd[tid] = s; __syncthreads();
  for (int st = 512; st > 0; st >>= 1) {
    if (tid < st) sd[tid] += sd[tid + st];
    __syncthreads();
  }
  const float total_sq = sd[0];
  __syncthreads();

  const float c = cs[tid];
  sd[tid] = c; __syncthreads();
  for (int st = 512; st > 0; st >>= 1) {
    if (tid < st) sd[tid] += sd[tid + st];
    __syncthreads();
  }
  const float S = sd[0];
  __syncthreads();

  const float p = c / (S + 1e-5f);
  sd[tid] = p * logf(p + 1e-5f);
  __syncthreads();
  for (int st = 512; st > 0; st >>= 1) {
    if (tid < st) sd[tid] += sd[tid + st];
    __syncthreads();
  }
  const float T = sd[0];
  __syncthreads();

  sd[tid] = (c > 1e-5f) ? 1.f : 0.f;
  __syncthreads();
  for (int st = 512; st > 0; st >>= 1) {
    if (tid < st) sd[tid] += sd[tid + st];
    __syncthreads();
  }
  const float U = sd[0];

  if (tid == 0) {
    out_s[0] = 1.25f * total_sq * inv_count;  // e_latent + 0.25*q_latent
    out_s[1] = expf(-T);                      // perplexity
    out_s[2] = U * (1.f / 1024.f);            // code usage rate
  }
}

// ---------------------------------------------------------------- launch
extern "C" void kernel_launch(void* const* d_in, const int* in_sizes, int n_in,
                              void* d_out, int out_size, void* d_ws, size_t ws_size,
                              hipStream_t stream) {
  const float* x   = (const float*)d_in[0];
  const float* emb = (const float*)d_in[1];
  const float* cs  = (const float*)d_in[2];
  float* out = (float*)d_out;

  const int N = in_sizes[0] / DIM;          // 32768
  const size_t ND = (size_t)N * DIM;        // 8388608

  float* enorm   = (float*)d_ws;                                           // 4 KB
  int*   idxw    = (int*)((char*)d_ws + NK * sizeof(float));               // 128 KB
  float* partial = (float*)((char*)d_ws + NK * sizeof(float) + (size_t)N * sizeof(int)); // 16 KB

  const int nGather = (int)(ND / 2048);     // 4096

  enorm_kernel<<<NK / 256, 256, 0, stream>>>(emb, enorm);
  argmin_kernel<<<N / RR, 256, 0, stream>>>(x, emb, enorm, idxw, out + ND + 3);
  gather_loss_kernel<<<nGather, 256, 0, stream>>>(x, emb, idxw, out, partial);
  finalize_kernel<<<1, 1024, 0, stream>>>(partial, nGather, cs, out + ND,
                                          1.0f / (float)ND);
}

// Round 11
// 290.573 us; speedup vs baseline: 1.2009x; 1.2009x over previous
//
#include <hip/hip_runtime.h>

// VQ-VAE vector quantizer forward (fp32).
// inputs: (32,256,32,32) f32 -> flat rows N=32768 x D=256
// embedding: (D=256, K=1024) f32, cluster_size: (1024,) f32
// outputs (flat f32): quantized[N*D], vq_loss, perplexity, code_usage, indices[N] (as float)

constexpr int DIM = 256;   // embedding dim
constexpr int NK  = 1024;  // number of codes
constexpr int RR  = 8;     // input rows per block (R10 post-mortem: 16 -> SGPR spill)

// async 16B global->LDS. HW dest = wave-uniform base + lane*16; all call
// sites pass exactly base + 16*lane (k0 = tid*4 floats).
#define GLL16(GSRC, LDST)                                                      \
  __builtin_amdgcn_global_load_lds(                                            \
      (const __attribute__((address_space(1))) void*)(GSRC),                   \
      (__attribute__((address_space(3))) void*)(LDST), 16, 0, 0)

#define SB __builtin_amdgcn_sched_barrier(0);

// ---------------------------------------------------------------- enorm (0.5*|e_k|^2)
__global__ __launch_bounds__(256) void enorm_kernel(
    const float* __restrict__ emb, float* __restrict__ enorm) {
  int k = blockIdx.x * 256 + threadIdx.x;
  float s = 0.f;
  for (int d = 0; d < DIM; ++d) {
    float e = emb[(size_t)d * NK + k];
    s = fmaf(e, e, s);
  }
  enorm[k] = 0.5f * s;                   // argmin(|e|^2-2x.e) == argmin(0.5|e|^2-x.e)
}

// ---------------------------------------------------------------- argmin
// 256 threads = 4 waves; 8 rows/block; thread owns codes k0..k0+3 (k0=4*tid).
// x is block-uniform -> s_load into SGPRs (R10-verified codegen), xA/xB
// ping-pong, 64 SGPRs total (fits: R10's RR=16 needed 128 -> spilled).
// es: R5/R10-proven self-staged global_load_lds double-buffer; vmcnt FIFO
// contains ONLY the stage quads (x is SMEM/lgkmcnt) -> counted vmcnt(4).
// Phase order: es ds_reads -> lgkmcnt(0) -> issue next x s_loads -> FMA
// block, so s_loads get a full FMA block of slack before the next phase's
// lgkmcnt(0) (SMEM+DS share lgkmcnt; SMEM is unordered -> 0 is forced).
#define STAGE(G, P)                                                            \
  { const float* _s = emb + ((size_t)(4 * (G)) << 10) + k0;                    \
    GLL16(_s,          &es[(P)][0][k0]);                                       \
    GLL16(_s + NK,     &es[(P)][1][k0]);                                       \
    GLL16(_s + 2 * NK, &es[(P)][2][k0]);                                       \
    GLL16(_s + 3 * NK, &es[(P)][3][k0]); }

#define XLOAD(XA, G)                                                           \
  _Pragma("unroll")                                                            \
  for (int r = 0; r < RR; ++r)                                                 \
    XA[r] = *(const float4*)&xg[r * DIM + 4 * (G)];

#define FMA8(XA)                                                               \
  _Pragma("unroll")                                                            \
  for (int r = 0; r < RR; ++r) {                                               \
    const float4 xv = XA[r];                                                   \
    acc[r][0] = fmaf(xv.x, e0.x, fmaf(xv.y, e1.x, fmaf(xv.z, e2.x, fmaf(xv.w, e3.x, acc[r][0])))); \
    acc[r][1] = fmaf(xv.x, e0.y, fmaf(xv.y, e1.y, fmaf(xv.z, e2.y, fmaf(xv.w, e3.y, acc[r][1])))); \
    acc[r][2] = fmaf(xv.x, e0.z, fmaf(xv.y, e1.z, fmaf(xv.z, e2.z, fmaf(xv.w, e3.z, acc[r][2])))); \
    acc[r][3] = fmaf(xv.x, e0.w, fmaf(xv.y, e1.w, fmaf(xv.z, e2.w, fmaf(xv.w, e3.w, acc[r][3])))); \
  }

__global__ __launch_bounds__(256, 4) void argmin_kernel(
    const float* __restrict__ x, const float* __restrict__ emb,
    const float* __restrict__ enorm, int* __restrict__ idx_out,
    float* __restrict__ idx_out_f) {
  __shared__ float es[2][4][NK];   // 32 KB double-buffered e-tile
  __shared__ float red_v[4][RR];
  __shared__ int   red_i[4][RR];

  const int tid  = threadIdx.x;
  const int lane = tid & 63;
  const int wv   = tid >> 6;
  const int k0   = tid * 4;
  const float* xg = x + (size_t)blockIdx.x * (RR * DIM);   // block-uniform base

  STAGE(0, 0)
  STAGE(1, 1)

  float4 xA[RR], xB[RR];
  XLOAD(xA, 0)

  float acc[RR][4];
  #pragma unroll
  for (int r = 0; r < RR; ++r)
    #pragma unroll
    for (int j = 0; j < 4; ++j) acc[r][j] = 0.f;

  #pragma unroll 1
  for (int gg = 0; gg < 32; ++gg) {
    const int g0 = 2 * gg;       // even group, parity 0
    const int g1 = g0 + 1;       // odd group,  parity 1

    { // ---- even phase: FIFO [S(g0)x4, S(g1)x4] -> drain S(g0)
      asm volatile("s_waitcnt vmcnt(4)" ::: "memory");
      SB
      const float4 e0 = *(const float4*)&es[0][0][k0];
      const float4 e1 = *(const float4*)&es[0][1][k0];
      const float4 e2 = *(const float4*)&es[0][2][k0];
      const float4 e3 = *(const float4*)&es[0][3][k0];
      asm volatile("s_waitcnt lgkmcnt(0)" ::: "memory");
      SB
      XLOAD(xB, g1)          // s_loads: full FMA block of slack below
      SB
      FMA8(xA)
      SB
      if (gg <= 30) STAGE(g0 + 2, 0)   // FIFO back to 8
    }
    { // ---- odd phase: drain S(g1), leave S(g0+2)
      if (gg < 31) { asm volatile("s_waitcnt vmcnt(4)" ::: "memory"); }
      else         { asm volatile("s_waitcnt vmcnt(0)" ::: "memory"); }
      SB
      const float4 e0 = *(const float4*)&es[1][0][k0];
      const float4 e1 = *(const float4*)&es[1][1][k0];
      const float4 e2 = *(const float4*)&es[1][2][k0];
      const float4 e3 = *(const float4*)&es[1][3][k0];
      asm volatile("s_waitcnt lgkmcnt(0)" ::: "memory");
      SB
      if (gg <= 30) { XLOAD(xA, g0 + 2) SB }
      FMA8(xB)
      SB
      if (gg <= 30) STAGE(g1 + 2, 1)
    }
  }

  const float4 en = *(const float4*)(enorm + k0);   // 0.5*|e|^2

  for (int r = 0; r < RR; ++r) {
    // score = 0.5|e|^2 - x.e ; strict < keeps lowest index on ties
    float bv = en.x - acc[r][0];
    int   bi = k0;
    { float v = en.y - acc[r][1]; if (v < bv) { bv = v; bi = k0 + 1; } }
    { float v = en.z - acc[r][2]; if (v < bv) { bv = v; bi = k0 + 2; } }
    { float v = en.w - acc[r][3]; if (v < bv) { bv = v; bi = k0 + 3; } }
    for (int off = 32; off > 0; off >>= 1) {
      float ov = __shfl_xor(bv, off);
      int   oi = __shfl_xor(bi, off);
      if (ov < bv || (ov == bv && oi < bi)) { bv = ov; bi = oi; }
    }
    if (lane == 0) { red_v[wv][r] = bv; red_i[wv][r] = bi; }
  }
  __syncthreads();

  if (tid < RR) {
    float bv = red_v[0][tid];
    int   bi = red_i[0][tid];
    #pragma unroll
    for (int w = 1; w < 4; ++w) {
      float v = red_v[w][tid]; int i2 = red_i[w][tid];
      if (v < bv || (v == bv && i2 < bi)) { bv = v; bi = i2; }
    }
    const int n = blockIdx.x * RR + tid;
    idx_out[n]   = bi;
    idx_out_f[n] = (float)bi;
  }
}

// ---------------------------------------------------------------- gather + loss partials
__global__ __launch_bounds__(256) void gather_loss_kernel(
    const float* __restrict__ x, const float* __restrict__ emb,
    const int* __restrict__ idx, float* __restrict__ out_q,
    float* __restrict__ partial) {
  const int tid = threadIdx.x;
  const size_t base = (size_t)blockIdx.x * 2048;
  float local = 0.f;
  #pragma unroll
  for (int h = 0; h < 2; ++h) {
    const size_t g = base + (size_t)h * 1024 + (size_t)tid * 4;
    const int n = (int)(g >> 8);
    const int d = (int)(g & 255);
    const int k = idx[n];
    const float* ep = emb + (size_t)d * NK + k;
    float4 q;
    q.x = ep[0]; q.y = ep[NK]; q.z = ep[2 * NK]; q.w = ep[3 * NK];
    const float4 xv = *(const float4*)(x + g);
    *(float4*)(out_q + g) = q;
    const float dx = q.x - xv.x, dy = q.y - xv.y, dz = q.z - xv.z, dw = q.w - xv.w;
    local = fmaf(dx, dx, local);
    local = fmaf(dy, dy, local);
    local = fmaf(dz, dz, local);
    local = fmaf(dw, dw, local);
  }
  for (int off = 32; off > 0; off >>= 1) local += __shfl_down(local, off);
  __shared__ float wsum[4];
  if ((tid & 63) == 0) wsum[tid >> 6] = local;
  __syncthreads();
  if (tid == 0) partial[blockIdx.x] = (wsum[0] + wsum[1]) + (wsum[2] + wsum[3]);
}

// ---------------------------------------------------------------- finalize scalars
__global__ __launch_bounds__(1024) void finalize_kernel(
    const float* __restrict__ partial, int np,
    const float* __restrict__ cs, float* __restrict__ out_s,
    float inv_count) {
  __shared__ float sd[1024];
  const int tid = threadIdx.x;

  float s = 0.f;
  for (int i = tid; i < np; i += 1024) s += partial[i];
  sd[tid] = s; __syncthreads();
  for (int st = 512; st > 0; st >>= 1) {
    if (tid < st) sd[tid] += sd[tid + st];
    __syncthreads();
  }
  const float total_sq = sd[0];
  __syncthreads();

  const float c = cs[tid];
  sd[tid] = c; __syncthreads();
  for (int st = 512; st > 0; st >>= 1) {
    if (tid < st) sd[tid] += sd[tid + st];
    __syncthreads();
  }
  const float S = sd[0];
  __syncthreads();

  const float p = c / (S + 1e-5f);
  sd[tid] = p * logf(p + 1e-5f);
  __syncthreads();
  for (int st = 512; st > 0; st >>= 1) {
    if (tid < st) sd[tid] += sd[tid + st];
    __syncthreads();
  }
  const float T = sd[0];
  __syncthreads();

  sd[tid] = (c > 1e-5f) ? 1.f : 0.f;
  __syncthreads();
  for (int st = 512; st > 0; st >>= 1) {
    if (tid < st) sd[tid] += sd[tid + st];
    __syncthreads();
  }
  const float U = sd[0];

  if (tid == 0) {
    out_s[0] = 1.25f * total_sq * inv_count;  // e_latent + 0.25*q_latent
    out_s[1] = expf(-T);                      // perplexity
    out_s[2] = U * (1.f / 1024.f);            // code usage rate
  }
}

// ---------------------------------------------------------------- launch
extern "C" void kernel_launch(void* const* d_in, const int* in_sizes, int n_in,
                              void* d_out, int out_size, void* d_ws, size_t ws_size,
                              hipStream_t stream) {
  const float* x   = (const float*)d_in[0];
  const float* emb = (const float*)d_in[1];
  const float* cs  = (const float*)d_in[2];
  float* out = (float*)d_out;

  const int N = in_sizes[0] / DIM;          // 32768
  const size_t ND = (size_t)N * DIM;        // 8388608

  float* enorm   = (float*)d_ws;                                           // 4 KB
  int*   idxw    = (int*)((char*)d_ws + NK * sizeof(float));               // 128 KB
  float* partial = (float*)((char*)d_ws + NK * sizeof(float) + (size_t)N * sizeof(int)); // 16 KB

  const int nGather = (int)(ND / 2048);     // 4096

  enorm_kernel<<<NK / 256, 256, 0, stream>>>(emb, enorm);
  argmin_kernel<<<N / RR, 256, 0, stream>>>(x, emb, enorm, idxw, out + ND + 3);
  gather_loss_kernel<<<nGather, 256, 0, stream>>>(x, emb, idxw, out, partial);
  finalize_kernel<<<1, 1024, 0, stream>>>(partial, nGather, cs, out + ND,
                                          1.0f / (float)ND);
}